// Round 12
// baseline (532.702 us; speedup 1.0000x reference)
//
#include <hip/hip_runtime.h>

#define VV 512
#define FF 64
#define OO 64
#define YELEMS 8388608  // elems per y tensor (256*512*64)

// ---- workspace layout (bytes) ----
#define C1_OFF    0u
#define C2_OFF    67108864u
#define Y1F8_OFF  134217728u   // also aliases atT (A^T bf16, 8MB) during att->coef
#define Y2F8_OFF  142606336u
#define YVO_OFF   150994944u   // y_vo bf16 [k][bt][v][o], 3*16.78MB
#define DEGP_OFF  201326592u
#define SDG_OFF   205520896u
#define ADG_OFF   206045184u
#define WS_NEED   206569472u

using f32x4  = __attribute__((ext_vector_type(4))) float;
using f32x16 = __attribute__((ext_vector_type(16))) float;
using s16x8  = __attribute__((ext_vector_type(8))) short;
using s16x4  = __attribute__((ext_vector_type(4))) short;
using u16x4  = __attribute__((ext_vector_type(4))) unsigned short;
using i64x2  = __attribute__((ext_vector_type(2))) long;

__device__ __forceinline__ short f2bf(float f) {
    union { float f; unsigned int u; } v; v.f = f;
    unsigned int u = v.u;
    u += 0x7fffu + ((u >> 16) & 1u);
    return (short)(u >> 16);
}
__device__ __forceinline__ float bf2f(unsigned short u) {
    union { unsigned int u; float f; } v; v.u = ((unsigned int)u) << 16; return v.f;
}
__device__ __forceinline__ int swz(int row) { return (row >> 1) & 7; }

__device__ __forceinline__ void gload16(const void* g, void* l) {
    __builtin_amdgcn_global_load_lds(
        (const __attribute__((address_space(1))) unsigned int*)g,
        (__attribute__((address_space(3))) unsigned int*)l, 16, 0, 0);
}

// =====================================================================
// Kernel A0: A^T bf16 precompute. atT[b][v][u] = Att[b][u][v].
// Lives in the Y1F8 region (dead before y_kernel2 writes it).
// =====================================================================
__global__ __launch_bounds__(256, 4)
void att_kernel(const float* __restrict__ Att, unsigned char* __restrict__ ws)
{
    __shared__ float T[64][65];
    const int tid = threadIdx.x;
    const int b  = blockIdx.x >> 6;
    const int ij = blockIdx.x & 63;
    const int i = ij >> 3, j = ij & 7;
    const float* Ab = Att + (size_t)b * VV * VV;
    const int r = tid >> 2, c4 = (tid & 3) * 16;
    const float* src = Ab + (size_t)(i * 64 + r) * VV + j * 64 + c4;
    #pragma unroll
    for (int w = 0; w < 4; ++w) {
        float4 t = ((const float4*)src)[w];
        T[r][c4 + w * 4 + 0] = t.x; T[r][c4 + w * 4 + 1] = t.y;
        T[r][c4 + w * 4 + 2] = t.z; T[r][c4 + w * 4 + 3] = t.w;
    }
    __syncthreads();
    unsigned short* dst = (unsigned short*)(ws + Y1F8_OFF) + (size_t)b * (VV * VV)
                        + (size_t)(j * 64 + r) * VV + i * 64 + c4;
    s16x8 p0, p1;
    #pragma unroll
    for (int e = 0; e < 8; ++e) {
        p0[e] = f2bf(T[c4 + e][r]);
        p1[e] = f2bf(T[c4 + 8 + e][r]);
    }
    *(s16x8*)dst = p0;
    *(s16x8*)(dst + 8) = p1;
}

// =====================================================================
// Kernel A (v4): barrier-free, LDS-free streaming coefficient kernel.
// Block = (bt, 64-v strip), same decode as cheb_b (8 strips of one bt
// co-resident on one XCD -> second S orientation served from L2).
// Wave Q owns u-quarter [Q*128, Q*128+128). Per u: col side is a
// coalesced 256B load (lane = v); row side is a per-thread row walk.
// u visited even-octets-then-odd so fp8 stores are contiguous int4 in
// the cheb_b-permuted layout du = par*256 + (bu>>4)*8.
// =====================================================================
__global__ __launch_bounds__(256, 6)
void coef_kernel(const float* __restrict__ S, const float* __restrict__ Att,
                 unsigned char* __restrict__ ws)
{
    const int tid = threadIdx.x, lane = tid & 63, Q = tid >> 6;

    const int wg = blockIdx.x;
    const int bt = (wg & 7) + ((wg >> 6) << 3);
    const int vt = (wg >> 3) & 7;
    const int v0 = vt * 64;
    const int b  = bt >> 4;
    const int v  = v0 + lane;               // my output row (global v)

    const float* Sbt = S + (size_t)bt * VV * VV;
    const float* Abt = Att + (size_t)b * VV * VV;
    const unsigned short* arow = (const unsigned short*)(ws + Y1F8_OFF)
                               + (size_t)b * (VV * VV) + (size_t)v * VV;
    const float* srow = Sbt + (size_t)v * VV;
    const float* scol = Sbt + v;

    unsigned char* c1r = ws + C1_OFF + (size_t)bt * (VV * VV) + (size_t)v * VV;
    unsigned char* c2r = ws + C2_OFF + (size_t)bt * (VV * VV) + (size_t)v * VV;
    float* degpW = (float*)(ws + DEGP_OFF) + (size_t)bt * 8 * VV;

    // exact f32 diagonal terms (once per (bt,v); this block owns the strip)
    if (tid < 64) {
        ((float*)(ws + SDG_OFF))[(size_t)bt * VV + v] = Sbt[(size_t)v * VV + v];
        ((float*)(ws + ADG_OFF))[(size_t)bt * VV + v] = Abt[(size_t)v * VV + v];
    }

    const int ub0 = Q * 128;
    float deg = 0.f;

    #pragma unroll
    for (int par = 0; par < 2; ++par) {
        #pragma unroll
        for (int pp = 0; pp < 4; ++pp) {
            const int bu = ub0 + par * 8 + pp * 32;
            // col side: 16 coalesced 4B loads (all lanes same u, lane = v)
            float sc[16];
            #pragma unroll
            for (int o = 0; o < 2; ++o)
                #pragma unroll
                for (int e = 0; e < 8; ++e)
                    sc[o * 8 + e] = scol[(size_t)(bu + o * 16 + e) * VV];
            // row side: per-thread 32B chunks of my own S row
            f32x4 r0 = *(const f32x4*)(srow + bu);
            f32x4 r1 = *(const f32x4*)(srow + bu + 4);
            f32x4 r2 = *(const f32x4*)(srow + bu + 16);
            f32x4 r3 = *(const f32x4*)(srow + bu + 20);
            // A^T row: contiguous bf16
            s16x8 a0 = *(const s16x8*)(arow + bu);
            s16x8 a1v = *(const s16x8*)(arow + bu + 16);

            int w1[4], w2[4];
            #pragma unroll
            for (int o = 0; o < 2; ++o) {
                float c1v[8], c2v[8];
                #pragma unroll
                for (int e = 0; e < 8; ++e) {
                    const int u = bu + o * 16 + e;
                    float rv = (o == 0) ? ((e < 4) ? r0[e] : r1[e - 4])
                                        : ((e < 4) ? r2[e] : r3[e - 4]);
                    float a  = bf2f((unsigned short)((o == 0) ? a0[e] : a1v[e]));
                    float sm = fminf(sc[o * 8 + e], rv);
                    deg += sm;
                    float c1 = -a * sm;
                    float c2 = (a + a) * (sm * sm);
                    if (u == v) { c1 = 0.f; c2 = 0.f; }
                    c1v[e] = c1; c2v[e] = c2;
                }
                int p0 = __builtin_amdgcn_cvt_pk_fp8_f32(c1v[0], c1v[1], 0, false);
                p0     = __builtin_amdgcn_cvt_pk_fp8_f32(c1v[2], c1v[3], p0, true);
                int p1 = __builtin_amdgcn_cvt_pk_fp8_f32(c1v[4], c1v[5], 0, false);
                p1     = __builtin_amdgcn_cvt_pk_fp8_f32(c1v[6], c1v[7], p1, true);
                int q0 = __builtin_amdgcn_cvt_pk_fp8_f32(c2v[0], c2v[1], 0, false);
                q0     = __builtin_amdgcn_cvt_pk_fp8_f32(c2v[2], c2v[3], q0, true);
                int q1 = __builtin_amdgcn_cvt_pk_fp8_f32(c2v[4], c2v[5], 0, false);
                q1     = __builtin_amdgcn_cvt_pk_fp8_f32(c2v[6], c2v[7], q1, true);
                w1[o * 2] = p0; w1[o * 2 + 1] = p1;
                w2[o * 2] = q0; w2[o * 2 + 1] = q1;
            }
            const int du = par * 256 + ((bu >> 4) * 8);
            int4 s1 = { w1[0], w1[1], w1[2], w1[3] };
            int4 s2 = { w2[0], w2[1], w2[2], w2[3] };
            *(int4*)(c1r + du) = s1;
            *(int4*)(c2r + du) = s2;
        }
    }

    degpW[(size_t)Q * VV + v] = deg;   // quarter partials, slots 0..3
}

// =====================================================================
// Kernel A': y_k = x @ Theta_k ; y_vo bf16 [k][bt][v][o] + fp8 images
// =====================================================================
__global__ __launch_bounds__(256, 4)
void y_kernel2(const float* __restrict__ x, const float* __restrict__ Theta,
               unsigned char* __restrict__ ws)
{
    __shared__ __align__(16) unsigned char smem[32768];
    short* xT = (short*)(smem);

    const int tid = threadIdx.x, lane = tid & 63, q = tid >> 6;
    const int g = lane >> 4, nbase = lane & 15;
    const int bt = blockIdx.x >> 3;
    const int u0 = (blockIdx.x & 7) * 64;

    {
        const float* xp = x + ((size_t)(bt * VV + u0 + lane)) * FF + q * 16;
        float4 a0 = ((const float4*)xp)[0];
        float4 a1 = ((const float4*)xp)[1];
        float4 a2 = ((const float4*)xp)[2];
        float4 a3 = ((const float4*)xp)[3];
        float v[16] = {a0.x,a0.y,a0.z,a0.w, a1.x,a1.y,a1.z,a1.w,
                       a2.x,a2.y,a2.z,a2.w, a3.x,a3.y,a3.z,a3.w};
        s16x8 p0, p1;
        #pragma unroll
        for (int e = 0; e < 8; ++e) { p0[e] = f2bf(v[e]); p1[e] = f2bf(v[8 + e]); }
        const int fs = swz(lane);
        *(s16x8*)&xT[lane * 64 + (((q * 2)     ^ fs) * 8)] = p0;
        *(s16x8*)&xT[lane * 64 + (((q * 2 + 1) ^ fs) * 8)] = p1;
    }
    #pragma unroll
    for (int k = 0; k < 3; ++k) {
        short* tk = (short*)(smem + 8192 + k * 8192);
        s16x8 p0, p1;
        #pragma unroll
        for (int e = 0; e < 8; ++e) {
            p0[e] = f2bf(Theta[k * FF * OO + (q * 16 + e) * OO + lane]);
            p1[e] = f2bf(Theta[k * FF * OO + (q * 16 + 8 + e) * OO + lane]);
        }
        const int fs = swz(lane);
        *(s16x8*)&tk[lane * 64 + (((q * 2)     ^ fs) * 8)] = p0;
        *(s16x8*)&tk[lane * 64 + (((q * 2 + 1) ^ fs) * 8)] = p1;
    }
    __syncthreads();

    f32x4 zero = {0.f, 0.f, 0.f, 0.f};
    f32x4 acc[3][4];
    #pragma unroll
    for (int k = 0; k < 3; ++k)
        #pragma unroll
        for (int nt = 0; nt < 4; ++nt) acc[k][nt] = zero;

    const int mrow = q * 16 + nbase;
    const int moff = mrow * 64, ms = swz(mrow);
    #pragma unroll
    for (int kk = 0; kk < 2; ++kk) {
        const int slotA = kk * 4 + g;
        s16x8 a = *(const s16x8*)&xT[moff + ((slotA ^ ms) * 8)];
        #pragma unroll
        for (int nt = 0; nt < 4; ++nt) {
            const int nrow = nt * 16 + nbase;
            const int nad = nrow * 64 + ((slotA ^ swz(nrow)) * 8);
            #pragma unroll
            for (int k = 0; k < 3; ++k) {
                s16x8 bb = *(const s16x8*)&((short*)(smem + 8192 + k * 8192))[nad];
                acc[k][nt] = __builtin_amdgcn_mfma_f32_16x16x32_bf16(a, bb, acc[k][nt], 0, 0, 0);
            }
        }
    }
    unsigned short* yvo = (unsigned short*)(ws + YVO_OFF);
    unsigned char* y1f8 = ws + Y1F8_OFF + (size_t)bt * 32768;
    unsigned char* y2f8 = ws + Y2F8_OFF + (size_t)bt * 32768;
    #pragma unroll
    for (int k = 0; k < 3; ++k) {
        #pragma unroll
        for (int nt = 0; nt < 4; ++nt) {
            const int o = nt * 16 + nbase;
            const int u = u0 + q * 16 + g * 4;   // v index of y_vo
            #pragma unroll
            for (int r = 0; r < 4; ++r)
                yvo[(size_t)k * YELEMS + (size_t)bt * 32768 + (size_t)(u + r) * OO + o] =
                    (unsigned short)f2bf(acc[k][nt][r]);
            if (k >= 1) {
                const int s = u >> 3;
                const int sw = (s & ~15) | ((s & 15) ^ (o & 15));
                const int ad = o * 512 + sw * 8 + (u & 4);
                int w = __builtin_amdgcn_cvt_pk_fp8_f32(acc[k][nt][0], acc[k][nt][1], 0, false);
                w     = __builtin_amdgcn_cvt_pk_fp8_f32(acc[k][nt][2], acc[k][nt][3], w, true);
                if (k == 1) *(int*)(y1f8 + ad) = w;
                else        *(int*)(y2f8 + ad) = w;
            }
        }
    }
}

// =====================================================================
// Kernel B: fp8 GEMM via mfma_f32_32x32x16_fp8_fp8.
// (deg now summed over 4 quarter-slots from coef v4)
// =====================================================================
__global__ __launch_bounds__(256, 2)
void cheb_b(const unsigned char* __restrict__ ws, float* __restrict__ out)
{
    __shared__ __align__(16) unsigned char yLds[65536];  // y1 | y2 images

    const int tid = threadIdx.x, lane = tid & 63;
    const int wv = tid >> 6;
    const int vh = wv >> 1, oh = wv & 1;
    const int rl = lane & 31, hi = lane >> 5;

    const int wg = blockIdx.x;
    const int bt = (wg & 7) + ((wg >> 6) << 3);
    const int vt = (wg >> 3) & 7;
    const int v0 = vt * 64;

    {
        const unsigned char* y1img = ws + Y1F8_OFF + (size_t)bt * 32768;
        const unsigned char* y2img = ws + Y2F8_OFF + (size_t)bt * 32768;
        const int wo = wv * 1024 + lane * 16;
        #pragma unroll
        for (int i = 0; i < 8; ++i) {
            gload16(y1img + i * 4096 + wo, (char*)yLds + i * 4096 + wv * 1024);
            gload16(y2img + i * 4096 + wo, (char*)yLds + 32768 + i * 4096 + wv * 1024);
        }
    }

    const size_t crow = (size_t)(v0 + vh * 32 + rl) * VV + hi * 256;
    const unsigned char* c1base = ws + C1_OFF + (size_t)bt * (VV * VV) + crow;
    const unsigned char* c2base = ws + C2_OFF + (size_t)bt * (VV * VV) + crow;
    i64x2 c1p[16], c2p[16];
    #pragma unroll
    for (int jj = 0; jj < 16; ++jj) {
        c1p[jj] = *(const i64x2*)(c1base + jj * 16);
        c2p[jj] = *(const i64x2*)(c2base + jj * 16);
    }

    __syncthreads();   // drains vmcnt(0): LDS staged + c-frags resident

    f32x16 acc;
    #pragma unroll
    for (int i = 0; i < 16; ++i) acc[i] = 0.f;

    const int yrow = (oh * 32 + rl) * 512;
    const int x15  = rl & 15;

    #pragma unroll
    for (int it = 0; it < 32; ++it) {
        const long a1 = c1p[it >> 1][it & 1];
        const long a2 = c2p[it >> 1][it & 1];
        const int s  = it * 2 + hi;
        const int sw = (s & ~15) | ((s & 15) ^ x15);
        const int ad = yrow + sw * 8;
        const long b1 = *(const long*)&yLds[ad];
        const long b2 = *(const long*)&yLds[32768 + ad];
        acc = __builtin_amdgcn_mfma_f32_32x32x16_fp8_fp8(a1, b1, acc, 0, 0, 0);
        acc = __builtin_amdgcn_mfma_f32_32x32x16_fp8_fp8(a2, b2, acc, 0, 0, 0);
    }

    __syncthreads();
    {
        float* ep = (float*)yLds;
        const float* degp = (const float*)(ws + DEGP_OFF) + (size_t)bt * 8 * VV;
        const float* SdgW = (const float*)(ws + SDG_OFF) + (size_t)bt * VV;
        const float* AdgW = (const float*)(ws + ADG_OFF) + (size_t)bt * VV;
        if (tid < 64) {
            float dv = 0.f;
            #pragma unroll
            for (int s = 0; s < 4; ++s) dv += degp[(size_t)s * VV + v0 + tid];
            ep[tid] = dv;
        } else if (tid < 128) {
            ep[64 + (tid - 64)] = SdgW[v0 + (tid - 64)];
        } else if (tid < 192) {
            ep[128 + (tid - 128)] = AdgW[v0 + (tid - 128)];
        }
    }
    __syncthreads();

    const float* ep = (const float*)yLds;
    const unsigned short* yvo = (const unsigned short*)(ws + YVO_OFF) + (size_t)bt * 32768;
    float* obt = out + (size_t)bt * VV * OO;
    const int o = oh * 32 + rl;

    #pragma unroll
    for (int r = 0; r < 16; ++r) {
        const int vloc = vh * 32 + (r & 3) + 8 * (r >> 2) + 4 * hi;
        const int vgr = v0 + vloc;
        const float dv = ep[vloc];
        const float Sd = ep[64 + vloc];
        const float Ad = ep[128 + vloc];
        const float Ld = dv - Sd - 1.0f;
        const float w1 = Ad * Ld;
        const float w2 = Ad * (2.0f * Ld * Ld - 1.0f);
        const size_t yi = (size_t)vgr * OO + o;
        float y0v = bf2f(yvo[yi]);
        float y1v = bf2f(yvo[(size_t)YELEMS + yi]);
        float y2v = bf2f(yvo[(size_t)2 * YELEMS + yi]);
        float val = acc[r] + Ad * y0v + w1 * y1v + w2 * y2v;
        obt[(size_t)vgr * OO + o] = fmaxf(val, 0.0f);
    }
}

// =====================================================================
// Fallback (R4 path, verbatim): used only if ws_size < WS_NEED
// =====================================================================
__global__ __launch_bounds__(256, 4)
void y_kernel_fb(const float* __restrict__ x, const float* __restrict__ Theta,
                 unsigned short* __restrict__ yT)
{
    __shared__ __align__(16) unsigned char smem[32768];
    short* xT = (short*)(smem);
    const int tid = threadIdx.x, lane = tid & 63, q = tid >> 6;
    const int g = lane >> 4, nbase = lane & 15;
    const int bt = blockIdx.x >> 3;
    const int u0 = (blockIdx.x & 7) * 64;
    {
        const float* xp = x + ((size_t)(bt * VV + u0 + lane)) * FF + q * 16;
        float4 a0 = ((const float4*)xp)[0];
        float4 a1 = ((const float4*)xp)[1];
        float4 a2 = ((const float4*)xp)[2];
        float4 a3 = ((const float4*)xp)[3];
        float v[16] = {a0.x,a0.y,a0.z,a0.w, a1.x,a1.y,a1.z,a1.w,
                       a2.x,a2.y,a2.z,a2.w, a3.x,a3.y,a3.z,a3.w};
        s16x8 p0, p1;
        #pragma unroll
        for (int e = 0; e < 8; ++e) { p0[e] = f2bf(v[e]); p1[e] = f2bf(v[8 + e]); }
        const int fs = swz(lane);
        *(s16x8*)&xT[lane * 64 + (((q * 2)     ^ fs) * 8)] = p0;
        *(s16x8*)&xT[lane * 64 + (((q * 2 + 1) ^ fs) * 8)] = p1;
    }
    #pragma unroll
    for (int k = 0; k < 3; ++k) {
        short* tk = (short*)(smem + 8192 + k * 8192);
        s16x8 p0, p1;
        #pragma unroll
        for (int e = 0; e < 8; ++e) {
            p0[e] = f2bf(Theta[k * FF * OO + (q * 16 + e) * OO + lane]);
            p1[e] = f2bf(Theta[k * FF * OO + (q * 16 + 8 + e) * OO + lane]);
        }
        const int fs = swz(lane);
        *(s16x8*)&tk[lane * 64 + (((q * 2)     ^ fs) * 8)] = p0;
        *(s16x8*)&tk[lane * 64 + (((q * 2 + 1) ^ fs) * 8)] = p1;
    }
    __syncthreads();
    f32x4 zero = {0.f, 0.f, 0.f, 0.f};
    f32x4 acc[3][4];
    #pragma unroll
    for (int k = 0; k < 3; ++k)
        #pragma unroll
        for (int nt = 0; nt < 4; ++nt) acc[k][nt] = zero;
    const int mrow = q * 16 + nbase;
    const int moff = mrow * 64, ms = swz(mrow);
    #pragma unroll
    for (int kk = 0; kk < 2; ++kk) {
        const int slotA = kk * 4 + g;
        s16x8 a = *(const s16x8*)&xT[moff + ((slotA ^ ms) * 8)];
        #pragma unroll
        for (int nt = 0; nt < 4; ++nt) {
            const int nrow = nt * 16 + nbase;
            const int nad = nrow * 64 + ((slotA ^ swz(nrow)) * 8);
            #pragma unroll
            for (int k = 0; k < 3; ++k) {
                s16x8 bb = *(const s16x8*)&((short*)(smem + 8192 + k * 8192))[nad];
                acc[k][nt] = __builtin_amdgcn_mfma_f32_16x16x32_bf16(a, bb, acc[k][nt], 0, 0, 0);
            }
        }
    }
    #pragma unroll
    for (int k = 0; k < 3; ++k) {
        #pragma unroll
        for (int nt = 0; nt < 4; ++nt) {
            const int o = nt * 16 + nbase;
            const int u = u0 + q * 16 + g * 4;
            u16x4 pk;
            #pragma unroll
            for (int r = 0; r < 4; ++r) pk[r] = (unsigned short)f2bf(acc[k][nt][r]);
            *(u16x4*)&yT[(size_t)k * YELEMS + ((size_t)(bt * 64 + o)) * VV + u] = pk;
        }
    }
}

__global__ __launch_bounds__(256, 4)
void cheb_main_fb(const float* __restrict__ S, const float* __restrict__ Att,
                  const unsigned short* __restrict__ yT, float* __restrict__ out)
{
    const int tid = threadIdx.x, lane = tid & 63, q = tid >> 6;
    const int g = lane >> 4, nbase = lane & 15;
    const int wg = blockIdx.x;
    const int bt = (wg & 7) + ((wg >> 6) << 3);
    const int vt = (wg >> 3) & 7;
    const int v0 = vt * 64;
    const int b  = bt >> 4;
    const float* Sbt = S + (size_t)bt * VV * VV;
    const float* Abt = Att + (size_t)b * VV * VV;
    const unsigned short* y0g = yT + (size_t)bt * 64 * VV;
    const unsigned short* y1g = y0g + (size_t)YELEMS;
    const unsigned short* y2g = y0g + (size_t)2 * YELEMS;
    const int mrow = q * 16 + nbase;
    const int vg   = v0 + mrow;
    const float* Srow = Sbt + (size_t)vg * VV;
    const float* Scol = Sbt + vg;
    const float* Acol = Abt + vg;
    f32x4 zero = {0.f, 0.f, 0.f, 0.f};
    f32x4 acc[4];
    #pragma unroll
    for (int i = 0; i < 4; ++i) acc[i] = zero;
    float da0 = 0.f, da1 = 0.f, adg = 0.f, sdg = 0.f;
    #pragma unroll
    for (int ut = 0; ut < 8; ++ut) {
        const int u0t = ut * 64;
        #pragma unroll
        for (int kk = 0; kk < 2; ++kk) {
            const int ub = u0t + (kk * 4 + g) * 8;
            s16x8 b10 = *(const s16x8*)&y1g[(size_t)(0 * 16 + nbase) * VV + ub];
            s16x8 b11 = *(const s16x8*)&y1g[(size_t)(1 * 16 + nbase) * VV + ub];
            s16x8 b12 = *(const s16x8*)&y1g[(size_t)(2 * 16 + nbase) * VV + ub];
            s16x8 b13 = *(const s16x8*)&y1g[(size_t)(3 * 16 + nbase) * VV + ub];
            f32x4 r0 = *(const f32x4*)(Srow + ub);
            f32x4 r1 = *(const f32x4*)(Srow + ub + 4);
            s16x8 a1, a2;
            #pragma unroll
            for (int e = 0; e < 8; ++e) {
                float sc = Scol[(size_t)(ub + e) * VV];
                float av = Acol[(size_t)(ub + e) * VV];
                float rv = (e < 4) ? r0[e] : r1[e - 4];
                float sm = fminf(sc, rv);
                if (e & 1) da1 += sm; else da0 += sm;
                float c1 = -av * sm;
                float c2 = (av + av) * (sm * sm);
                if (ub + e == vg) { c1 = 0.f; c2 = 0.f; adg = av; sdg = sm; }
                a1[e] = f2bf(c1);
                a2[e] = f2bf(c2);
            }
            acc[0] = __builtin_amdgcn_mfma_f32_16x16x32_bf16(a1, b10, acc[0], 0, 0, 0);
            acc[1] = __builtin_amdgcn_mfma_f32_16x16x32_bf16(a1, b11, acc[1], 0, 0, 0);
            acc[2] = __builtin_amdgcn_mfma_f32_16x16x32_bf16(a1, b12, acc[2], 0, 0, 0);
            acc[3] = __builtin_amdgcn_mfma_f32_16x16x32_bf16(a1, b13, acc[3], 0, 0, 0);
            s16x8 b20 = *(const s16x8*)&y2g[(size_t)(0 * 16 + nbase) * VV + ub];
            s16x8 b21 = *(const s16x8*)&y2g[(size_t)(1 * 16 + nbase) * VV + ub];
            s16x8 b22 = *(const s16x8*)&y2g[(size_t)(2 * 16 + nbase) * VV + ub];
            s16x8 b23 = *(const s16x8*)&y2g[(size_t)(3 * 16 + nbase) * VV + ub];
            acc[0] = __builtin_amdgcn_mfma_f32_16x16x32_bf16(a2, b20, acc[0], 0, 0, 0);
            acc[1] = __builtin_amdgcn_mfma_f32_16x16x32_bf16(a2, b21, acc[1], 0, 0, 0);
            acc[2] = __builtin_amdgcn_mfma_f32_16x16x32_bf16(a2, b22, acc[2], 0, 0, 0);
            acc[3] = __builtin_amdgcn_mfma_f32_16x16x32_bf16(a2, b23, acc[3], 0, 0, 0);
        }
    }
    float da = da0 + da1;
    da  += __shfl_xor(da, 16);  da  += __shfl_xor(da, 32);
    adg += __shfl_xor(adg, 16); adg += __shfl_xor(adg, 32);
    sdg += __shfl_xor(sdg, 16); sdg += __shfl_xor(sdg, 32);
    float* obt = out + (size_t)bt * VV * OO;
    #pragma unroll
    for (int r = 0; r < 4; ++r) {
        const int vloc = q * 16 + g * 4 + r;
        const int src  = g * 4 + r;
        const float Ad = __shfl(adg, src);
        const float dv = __shfl(da,  src);
        const float Sd = __shfl(sdg, src);
        const float Ld = dv - Sd - 1.0f;
        const float w1 = Ad * Ld;
        const float w2 = Ad * (2.0f * Ld * Ld - 1.0f);
        const int vgr = v0 + vloc;
        #pragma unroll
        for (int nt = 0; nt < 4; ++nt) {
            const int oo = nt * 16 + nbase;
            const size_t yi = (size_t)oo * VV + vgr;
            float y0v = bf2f(y0g[yi]);
            float y1v = bf2f(y1g[yi]);
            float y2v = bf2f(y2g[yi]);
            float val = acc[nt][r] + Ad * y0v + w1 * y1v + w2 * y2v;
            obt[(size_t)vgr * OO + oo] = fmaxf(val, 0.0f);
        }
    }
}

extern "C" void kernel_launch(void* const* d_in, const int* in_sizes, int n_in,
                              void* d_out, int out_size, void* d_ws, size_t ws_size,
                              hipStream_t stream) {
    (void)in_sizes; (void)n_in; (void)out_size;
    const float* x   = (const float*)d_in[0];
    const float* Att = (const float*)d_in[1];
    const float* S   = (const float*)d_in[2];
    const float* Th  = (const float*)d_in[3];
    float* outp = (float*)d_out;
    if (ws_size >= (size_t)WS_NEED) {
        unsigned char* ws = (unsigned char*)d_ws;
        hipLaunchKernelGGL(att_kernel, dim3(1024), dim3(256), 0, stream, Att, ws);
        hipLaunchKernelGGL(coef_kernel, dim3(2048), dim3(256), 0, stream, S, Att, ws);
        hipLaunchKernelGGL(y_kernel2, dim3(2048), dim3(256), 0, stream, x, Th, ws);
        hipLaunchKernelGGL(cheb_b, dim3(2048), dim3(256), 0, stream, ws, outp);
    } else {
        unsigned short* yT = (unsigned short*)d_ws;
        hipLaunchKernelGGL(y_kernel_fb, dim3(2048), dim3(256), 0, stream, x, Th, yT);
        hipLaunchKernelGGL(cheb_main_fb, dim3(2048), dim3(256), 0, stream, S, Att, yT, outp);
    }
}

// Round 13
// 223.193 us; speedup vs baseline: 2.3867x; 2.3867x over previous
//
#include <hip/hip_runtime.h>

#define VV 512
#define FF 64
#define OO 64
#define YELEMS 8388608  // elems per y tensor (256*512*64)

// ---- workspace layout (bytes) ----
#define C1_OFF    0u
#define C2_OFF    67108864u
#define Y1F8_OFF  134217728u   // also aliases atT (A^T bf16, 8MB) during att->coef
#define Y2F8_OFF  142606336u
#define YVO_OFF   150994944u   // y_vo bf16 [k][bt][v][o], 3*16.78MB
#define DEGP_OFF  201326592u
#define SDG_OFF   205520896u
#define ADG_OFF   206045184u
#define WS_NEED   206569472u

using f32x4  = __attribute__((ext_vector_type(4))) float;
using f32x16 = __attribute__((ext_vector_type(16))) float;
using s16x8  = __attribute__((ext_vector_type(8))) short;
using s16x4  = __attribute__((ext_vector_type(4))) short;
using u16x4  = __attribute__((ext_vector_type(4))) unsigned short;
using i64x2  = __attribute__((ext_vector_type(2))) long;

__device__ __forceinline__ short f2bf(float f) {
    union { float f; unsigned int u; } v; v.f = f;
    unsigned int u = v.u;
    u += 0x7fffu + ((u >> 16) & 1u);
    return (short)(u >> 16);
}
__device__ __forceinline__ float bf2f(unsigned short u) {
    union { unsigned int u; float f; } v; v.u = ((unsigned int)u) << 16; return v.f;
}
__device__ __forceinline__ int swz(int row) { return (row >> 1) & 7; }

__device__ __forceinline__ void gload16(const void* g, void* l) {
    __builtin_amdgcn_global_load_lds(
        (const __attribute__((address_space(1))) unsigned int*)g,
        (__attribute__((address_space(3))) unsigned int*)l, 16, 0, 0);
}

// =====================================================================
// Kernel A0: A^T bf16 precompute. atT[b][v][u] = Att[b][u][v].
// Lives in the Y1F8 region (dead before y_kernel2 writes it).
// =====================================================================
__global__ __launch_bounds__(256, 4)
void att_kernel(const float* __restrict__ Att, unsigned char* __restrict__ ws)
{
    __shared__ float T[64][65];
    const int tid = threadIdx.x;
    const int b  = blockIdx.x >> 6;
    const int ij = blockIdx.x & 63;
    const int i = ij >> 3, j = ij & 7;
    const float* Ab = Att + (size_t)b * VV * VV;
    const int r = tid >> 2, c4 = (tid & 3) * 16;
    const float* src = Ab + (size_t)(i * 64 + r) * VV + j * 64 + c4;
    #pragma unroll
    for (int w = 0; w < 4; ++w) {
        float4 t = ((const float4*)src)[w];
        T[r][c4 + w * 4 + 0] = t.x; T[r][c4 + w * 4 + 1] = t.y;
        T[r][c4 + w * 4 + 2] = t.z; T[r][c4 + w * 4 + 3] = t.w;
    }
    __syncthreads();
    unsigned short* dst = (unsigned short*)(ws + Y1F8_OFF) + (size_t)b * (VV * VV)
                        + (size_t)(j * 64 + r) * VV + i * 64 + c4;
    s16x8 p0, p1;
    #pragma unroll
    for (int e = 0; e < 8; ++e) {
        p0[e] = f2bf(T[c4 + e][r]);
        p1[e] = f2bf(T[c4 + 8 + e][r]);
    }
    *(s16x8*)dst = p0;
    *(s16x8*)(dst + 8) = p1;
}

// =====================================================================
// Kernel A (v5): coef tiles -> fp8, u-permuted rows [bt][v][u''].
// = v3 with ALL A^T fragment loads hoisted to block entry, issued
// BEFORE the S-tile staging so the single __syncthreads vmcnt-drain
// absorbs their latency (one latency exposure; pure LDS/VALU compute).
// =====================================================================
__global__ __launch_bounds__(256, 4)
void coef_kernel(const float* __restrict__ S, const float* __restrict__ Att,
                 unsigned char* __restrict__ ws)
{
    __shared__ float Sij[64][65];
    __shared__ float Sji[64][65];

    const int tid = threadIdx.x;
    const int bt = blockIdx.x / 36;
    int p = blockIdx.x - bt * 36;
    int i = 0;
    while (p >= 8 - i) { p -= 8 - i; ++i; }
    const int j = i + p;
    const int b = bt >> 4;
    const int u0i = i * 64, u0j = j * 64;

    const float* Sbt = S + (size_t)bt * VV * VV;
    const float* Abt = Att + (size_t)b * VV * VV;
    const unsigned short* atT = (const unsigned short*)(ws + Y1F8_OFF) + (size_t)b * (VV * VV);

    const int v  = tid >> 2;         // output row (local)
    const int sp = tid & 3;
    const int pr = sp >> 1, idx = sp & 1;
    const int sl0 = idx * 4 + pr;        // octet for t=0
    const int sl1 = idx * 4 + 2 + pr;    // octet for t=1

    // ---- HOISTED A^T loads (4x16B, independent; drain at the barrier) ----
    const unsigned short* ar0 = atT + (size_t)(u0j + v) * VV + u0i;   // pass0 rows
    const unsigned short* ar1 = atT + (size_t)(u0i + v) * VV + u0j;   // pass1 rows
    s16x8 a00 = *(const s16x8*)(ar0 + sl0 * 8);
    s16x8 a01 = *(const s16x8*)(ar0 + sl1 * 8);
    s16x8 a10 = *(const s16x8*)(ar1 + sl0 * 8);
    s16x8 a11 = *(const s16x8*)(ar1 + sl1 * 8);

    // ---- stage the two S tiles (f32) ----
    {
        const int r = tid >> 2, c4 = (tid & 3) * 16;
        const float* gij = Sbt + (size_t)(u0i + r) * VV + u0j + c4;
        const float* gji = Sbt + (size_t)(u0j + r) * VV + u0i + c4;
        #pragma unroll
        for (int w = 0; w < 4; ++w) {
            float4 t = ((const float4*)gij)[w];
            Sij[r][c4 + w * 4 + 0] = t.x; Sij[r][c4 + w * 4 + 1] = t.y;
            Sij[r][c4 + w * 4 + 2] = t.z; Sij[r][c4 + w * 4 + 3] = t.w;
        }
        #pragma unroll
        for (int w = 0; w < 4; ++w) {
            float4 t = ((const float4*)gji)[w];
            Sji[r][c4 + w * 4 + 0] = t.x; Sji[r][c4 + w * 4 + 1] = t.y;
            Sji[r][c4 + w * 4 + 2] = t.z; Sji[r][c4 + w * 4 + 3] = t.w;
        }
    }
    // exact f32 diagonal terms straight from global
    if (i == j && tid < 64) {
        const int vg = u0i + tid;
        ((float*)(ws + SDG_OFF))[(size_t)bt * VV + vg] = Sbt[(size_t)vg * VV + vg];
        ((float*)(ws + ADG_OFF))[(size_t)bt * VV + vg] = Abt[(size_t)vg * VV + vg];
    }
    __syncthreads();

    unsigned char* c1w = ws + C1_OFF + (size_t)bt * (VV * VV);
    unsigned char* c2w = ws + C2_OFF + (size_t)bt * (VV * VV);
    float* degpW = (float*)(ws + DEGP_OFF) + (size_t)bt * 8 * VV;

    #pragma unroll
    for (int pass = 0; pass < 2; ++pass) {
        if (pass == 1 && i == j) break;
        const float (*Tuv)[65] = (pass == 0) ? Sij : Sji;
        const float (*Tvu)[65] = (pass == 0) ? Sji : Sij;
        const int I = (pass == 0) ? i : j;
        const int J = (pass == 0) ? j : i;
        const bool dtile = (i == j);   // only possible in pass 0

        float degp = 0.f;
        int w1[4], w2[4];
        #pragma unroll
        for (int t = 0; t < 2; ++t) {
            const int sl = idx * 4 + t * 2 + pr;   // octet index
            // preloaded A^T fragment (static selection, loops unrolled)
            s16x8 a8 = (pass == 0) ? ((t == 0) ? a00 : a01)
                                   : ((t == 0) ? a10 : a11);
            float c1v[8], c2v[8];
            #pragma unroll
            for (int e = 0; e < 8; ++e) {
                const int u = sl * 8 + e;
                float sm = fminf(Tuv[u][v], Tvu[v][u]);
                float a  = bf2f((unsigned short)a8[e]);
                degp += sm;
                float c1 = -a * sm;
                float c2 = (a + a) * (sm * sm);
                if (dtile && (u == v)) { c1 = 0.f; c2 = 0.f; }
                c1v[e] = c1; c2v[e] = c2;
            }
            int a0 = __builtin_amdgcn_cvt_pk_fp8_f32(c1v[0], c1v[1], 0, false);
            a0     = __builtin_amdgcn_cvt_pk_fp8_f32(c1v[2], c1v[3], a0, true);
            int a1 = __builtin_amdgcn_cvt_pk_fp8_f32(c1v[4], c1v[5], 0, false);
            a1     = __builtin_amdgcn_cvt_pk_fp8_f32(c1v[6], c1v[7], a1, true);
            int b0 = __builtin_amdgcn_cvt_pk_fp8_f32(c2v[0], c2v[1], 0, false);
            b0     = __builtin_amdgcn_cvt_pk_fp8_f32(c2v[2], c2v[3], b0, true);
            int b1 = __builtin_amdgcn_cvt_pk_fp8_f32(c2v[4], c2v[5], 0, false);
            b1     = __builtin_amdgcn_cvt_pk_fp8_f32(c2v[6], c2v[7], b1, true);
            w1[t * 2] = a0; w1[t * 2 + 1] = a1;
            w2[t * 2] = b0; w2[t * 2 + 1] = b1;
        }
        const int vglob = J * 64 + v;
        const size_t rowoff = (size_t)vglob * VV + pr * 256 + I * 32 + idx * 16;
        int4 s1 = { w1[0], w1[1], w1[2], w1[3] };
        int4 s2 = { w2[0], w2[1], w2[2], w2[3] };
        *(int4*)(c1w + rowoff) = s1;
        *(int4*)(c2w + rowoff) = s2;

        degp += __shfl_xor(degp, 1);
        degp += __shfl_xor(degp, 2);
        if (sp == 0) degpW[(size_t)I * VV + vglob] = degp;
    }
}

// =====================================================================
// Kernel A': y_k = x @ Theta_k ; y_vo bf16 [k][bt][v][o] + fp8 images
// =====================================================================
__global__ __launch_bounds__(256, 4)
void y_kernel2(const float* __restrict__ x, const float* __restrict__ Theta,
               unsigned char* __restrict__ ws)
{
    __shared__ __align__(16) unsigned char smem[32768];
    short* xT = (short*)(smem);

    const int tid = threadIdx.x, lane = tid & 63, q = tid >> 6;
    const int g = lane >> 4, nbase = lane & 15;
    const int bt = blockIdx.x >> 3;
    const int u0 = (blockIdx.x & 7) * 64;

    {
        const float* xp = x + ((size_t)(bt * VV + u0 + lane)) * FF + q * 16;
        float4 a0 = ((const float4*)xp)[0];
        float4 a1 = ((const float4*)xp)[1];
        float4 a2 = ((const float4*)xp)[2];
        float4 a3 = ((const float4*)xp)[3];
        float v[16] = {a0.x,a0.y,a0.z,a0.w, a1.x,a1.y,a1.z,a1.w,
                       a2.x,a2.y,a2.z,a2.w, a3.x,a3.y,a3.z,a3.w};
        s16x8 p0, p1;
        #pragma unroll
        for (int e = 0; e < 8; ++e) { p0[e] = f2bf(v[e]); p1[e] = f2bf(v[8 + e]); }
        const int fs = swz(lane);
        *(s16x8*)&xT[lane * 64 + (((q * 2)     ^ fs) * 8)] = p0;
        *(s16x8*)&xT[lane * 64 + (((q * 2 + 1) ^ fs) * 8)] = p1;
    }
    #pragma unroll
    for (int k = 0; k < 3; ++k) {
        short* tk = (short*)(smem + 8192 + k * 8192);
        s16x8 p0, p1;
        #pragma unroll
        for (int e = 0; e < 8; ++e) {
            p0[e] = f2bf(Theta[k * FF * OO + (q * 16 + e) * OO + lane]);
            p1[e] = f2bf(Theta[k * FF * OO + (q * 16 + 8 + e) * OO + lane]);
        }
        const int fs = swz(lane);
        *(s16x8*)&tk[lane * 64 + (((q * 2)     ^ fs) * 8)] = p0;
        *(s16x8*)&tk[lane * 64 + (((q * 2 + 1) ^ fs) * 8)] = p1;
    }
    __syncthreads();

    f32x4 zero = {0.f, 0.f, 0.f, 0.f};
    f32x4 acc[3][4];
    #pragma unroll
    for (int k = 0; k < 3; ++k)
        #pragma unroll
        for (int nt = 0; nt < 4; ++nt) acc[k][nt] = zero;

    const int mrow = q * 16 + nbase;
    const int moff = mrow * 64, ms = swz(mrow);
    #pragma unroll
    for (int kk = 0; kk < 2; ++kk) {
        const int slotA = kk * 4 + g;
        s16x8 a = *(const s16x8*)&xT[moff + ((slotA ^ ms) * 8)];
        #pragma unroll
        for (int nt = 0; nt < 4; ++nt) {
            const int nrow = nt * 16 + nbase;
            const int nad = nrow * 64 + ((slotA ^ swz(nrow)) * 8);
            #pragma unroll
            for (int k = 0; k < 3; ++k) {
                s16x8 bb = *(const s16x8*)&((short*)(smem + 8192 + k * 8192))[nad];
                acc[k][nt] = __builtin_amdgcn_mfma_f32_16x16x32_bf16(a, bb, acc[k][nt], 0, 0, 0);
            }
        }
    }
    unsigned short* yvo = (unsigned short*)(ws + YVO_OFF);
    unsigned char* y1f8 = ws + Y1F8_OFF + (size_t)bt * 32768;
    unsigned char* y2f8 = ws + Y2F8_OFF + (size_t)bt * 32768;
    #pragma unroll
    for (int k = 0; k < 3; ++k) {
        #pragma unroll
        for (int nt = 0; nt < 4; ++nt) {
            const int o = nt * 16 + nbase;
            const int u = u0 + q * 16 + g * 4;   // v index of y_vo
            #pragma unroll
            for (int r = 0; r < 4; ++r)
                yvo[(size_t)k * YELEMS + (size_t)bt * 32768 + (size_t)(u + r) * OO + o] =
                    (unsigned short)f2bf(acc[k][nt][r]);
            if (k >= 1) {
                const int s = u >> 3;
                const int sw = (s & ~15) | ((s & 15) ^ (o & 15));
                const int ad = o * 512 + sw * 8 + (u & 4);
                int w = __builtin_amdgcn_cvt_pk_fp8_f32(acc[k][nt][0], acc[k][nt][1], 0, false);
                w     = __builtin_amdgcn_cvt_pk_fp8_f32(acc[k][nt][2], acc[k][nt][3], w, true);
                if (k == 1) *(int*)(y1f8 + ad) = w;
                else        *(int*)(y2f8 + ad) = w;
            }
        }
    }
}

// =====================================================================
// Kernel B: fp8 GEMM via mfma_f32_32x32x16_fp8_fp8. (deg: 8 slots)
// =====================================================================
__global__ __launch_bounds__(256, 2)
void cheb_b(const unsigned char* __restrict__ ws, float* __restrict__ out)
{
    __shared__ __align__(16) unsigned char yLds[65536];  // y1 | y2 images

    const int tid = threadIdx.x, lane = tid & 63;
    const int wv = tid >> 6;
    const int vh = wv >> 1, oh = wv & 1;
    const int rl = lane & 31, hi = lane >> 5;

    const int wg = blockIdx.x;
    const int bt = (wg & 7) + ((wg >> 6) << 3);
    const int vt = (wg >> 3) & 7;
    const int v0 = vt * 64;

    {
        const unsigned char* y1img = ws + Y1F8_OFF + (size_t)bt * 32768;
        const unsigned char* y2img = ws + Y2F8_OFF + (size_t)bt * 32768;
        const int wo = wv * 1024 + lane * 16;
        #pragma unroll
        for (int i = 0; i < 8; ++i) {
            gload16(y1img + i * 4096 + wo, (char*)yLds + i * 4096 + wv * 1024);
            gload16(y2img + i * 4096 + wo, (char*)yLds + 32768 + i * 4096 + wv * 1024);
        }
    }

    const size_t crow = (size_t)(v0 + vh * 32 + rl) * VV + hi * 256;
    const unsigned char* c1base = ws + C1_OFF + (size_t)bt * (VV * VV) + crow;
    const unsigned char* c2base = ws + C2_OFF + (size_t)bt * (VV * VV) + crow;
    i64x2 c1p[16], c2p[16];
    #pragma unroll
    for (int jj = 0; jj < 16; ++jj) {
        c1p[jj] = *(const i64x2*)(c1base + jj * 16);
        c2p[jj] = *(const i64x2*)(c2base + jj * 16);
    }

    __syncthreads();   // drains vmcnt(0): LDS staged + c-frags resident

    f32x16 acc;
    #pragma unroll
    for (int i = 0; i < 16; ++i) acc[i] = 0.f;

    const int yrow = (oh * 32 + rl) * 512;
    const int x15  = rl & 15;

    #pragma unroll
    for (int it = 0; it < 32; ++it) {
        const long a1 = c1p[it >> 1][it & 1];
        const long a2 = c2p[it >> 1][it & 1];
        const int s  = it * 2 + hi;
        const int sw = (s & ~15) | ((s & 15) ^ x15);
        const int ad = yrow + sw * 8;
        const long b1 = *(const long*)&yLds[ad];
        const long b2 = *(const long*)&yLds[32768 + ad];
        acc = __builtin_amdgcn_mfma_f32_32x32x16_fp8_fp8(a1, b1, acc, 0, 0, 0);
        acc = __builtin_amdgcn_mfma_f32_32x32x16_fp8_fp8(a2, b2, acc, 0, 0, 0);
    }

    __syncthreads();
    {
        float* ep = (float*)yLds;
        const float* degp = (const float*)(ws + DEGP_OFF) + (size_t)bt * 8 * VV;
        const float* SdgW = (const float*)(ws + SDG_OFF) + (size_t)bt * VV;
        const float* AdgW = (const float*)(ws + ADG_OFF) + (size_t)bt * VV;
        if (tid < 64) {
            float dv = 0.f;
            #pragma unroll
            for (int s = 0; s < 8; ++s) dv += degp[(size_t)s * VV + v0 + tid];
            ep[tid] = dv;
        } else if (tid < 128) {
            ep[64 + (tid - 64)] = SdgW[v0 + (tid - 64)];
        } else if (tid < 192) {
            ep[128 + (tid - 128)] = AdgW[v0 + (tid - 128)];
        }
    }
    __syncthreads();

    const float* ep = (const float*)yLds;
    const unsigned short* yvo = (const unsigned short*)(ws + YVO_OFF) + (size_t)bt * 32768;
    float* obt = out + (size_t)bt * VV * OO;
    const int o = oh * 32 + rl;

    #pragma unroll
    for (int r = 0; r < 16; ++r) {
        const int vloc = vh * 32 + (r & 3) + 8 * (r >> 2) + 4 * hi;
        const int vgr = v0 + vloc;
        const float dv = ep[vloc];
        const float Sd = ep[64 + vloc];
        const float Ad = ep[128 + vloc];
        const float Ld = dv - Sd - 1.0f;
        const float w1 = Ad * Ld;
        const float w2 = Ad * (2.0f * Ld * Ld - 1.0f);
        const size_t yi = (size_t)vgr * OO + o;
        float y0v = bf2f(yvo[yi]);
        float y1v = bf2f(yvo[(size_t)YELEMS + yi]);
        float y2v = bf2f(yvo[(size_t)2 * YELEMS + yi]);
        float val = acc[r] + Ad * y0v + w1 * y1v + w2 * y2v;
        obt[(size_t)vgr * OO + o] = fmaxf(val, 0.0f);
    }
}

// =====================================================================
// Fallback (R4 path, verbatim): used only if ws_size < WS_NEED
// =====================================================================
__global__ __launch_bounds__(256, 4)
void y_kernel_fb(const float* __restrict__ x, const float* __restrict__ Theta,
                 unsigned short* __restrict__ yT)
{
    __shared__ __align__(16) unsigned char smem[32768];
    short* xT = (short*)(smem);
    const int tid = threadIdx.x, lane = tid & 63, q = tid >> 6;
    const int g = lane >> 4, nbase = lane & 15;
    const int bt = blockIdx.x >> 3;
    const int u0 = (blockIdx.x & 7) * 64;
    {
        const float* xp = x + ((size_t)(bt * VV + u0 + lane)) * FF + q * 16;
        float4 a0 = ((const float4*)xp)[0];
        float4 a1 = ((const float4*)xp)[1];
        float4 a2 = ((const float4*)xp)[2];
        float4 a3 = ((const float4*)xp)[3];
        float v[16] = {a0.x,a0.y,a0.z,a0.w, a1.x,a1.y,a1.z,a1.w,
                       a2.x,a2.y,a2.z,a2.w, a3.x,a3.y,a3.z,a3.w};
        s16x8 p0, p1;
        #pragma unroll
        for (int e = 0; e < 8; ++e) { p0[e] = f2bf(v[e]); p1[e] = f2bf(v[8 + e]); }
        const int fs = swz(lane);
        *(s16x8*)&xT[lane * 64 + (((q * 2)     ^ fs) * 8)] = p0;
        *(s16x8*)&xT[lane * 64 + (((q * 2 + 1) ^ fs) * 8)] = p1;
    }
    #pragma unroll
    for (int k = 0; k < 3; ++k) {
        short* tk = (short*)(smem + 8192 + k * 8192);
        s16x8 p0, p1;
        #pragma unroll
        for (int e = 0; e < 8; ++e) {
            p0[e] = f2bf(Theta[k * FF * OO + (q * 16 + e) * OO + lane]);
            p1[e] = f2bf(Theta[k * FF * OO + (q * 16 + 8 + e) * OO + lane]);
        }
        const int fs = swz(lane);
        *(s16x8*)&tk[lane * 64 + (((q * 2)     ^ fs) * 8)] = p0;
        *(s16x8*)&tk[lane * 64 + (((q * 2 + 1) ^ fs) * 8)] = p1;
    }
    __syncthreads();
    f32x4 zero = {0.f, 0.f, 0.f, 0.f};
    f32x4 acc[3][4];
    #pragma unroll
    for (int k = 0; k < 3; ++k)
        #pragma unroll
        for (int nt = 0; nt < 4; ++nt) acc[k][nt] = zero;
    const int mrow = q * 16 + nbase;
    const int moff = mrow * 64, ms = swz(mrow);
    #pragma unroll
    for (int kk = 0; kk < 2; ++kk) {
        const int slotA = kk * 4 + g;
        s16x8 a = *(const s16x8*)&xT[moff + ((slotA ^ ms) * 8)];
        #pragma unroll
        for (int nt = 0; nt < 4; ++nt) {
            const int nrow = nt * 16 + nbase;
            const int nad = nrow * 64 + ((slotA ^ swz(nrow)) * 8);
            #pragma unroll
            for (int k = 0; k < 3; ++k) {
                s16x8 bb = *(const s16x8*)&((short*)(smem + 8192 + k * 8192))[nad];
                acc[k][nt] = __builtin_amdgcn_mfma_f32_16x16x32_bf16(a, bb, acc[k][nt], 0, 0, 0);
            }
        }
    }
    #pragma unroll
    for (int k = 0; k < 3; ++k) {
        #pragma unroll
        for (int nt = 0; nt < 4; ++nt) {
            const int o = nt * 16 + nbase;
            const int u = u0 + q * 16 + g * 4;
            u16x4 pk;
            #pragma unroll
            for (int r = 0; r < 4; ++r) pk[r] = (unsigned short)f2bf(acc[k][nt][r]);
            *(u16x4*)&yT[(size_t)k * YELEMS + ((size_t)(bt * 64 + o)) * VV + u] = pk;
        }
    }
}

__global__ __launch_bounds__(256, 4)
void cheb_main_fb(const float* __restrict__ S, const float* __restrict__ Att,
                  const unsigned short* __restrict__ yT, float* __restrict__ out)
{
    const int tid = threadIdx.x, lane = tid & 63, q = tid >> 6;
    const int g = lane >> 4, nbase = lane & 15;
    const int wg = blockIdx.x;
    const int bt = (wg & 7) + ((wg >> 6) << 3);
    const int vt = (wg >> 3) & 7;
    const int v0 = vt * 64;
    const int b  = bt >> 4;
    const float* Sbt = S + (size_t)bt * VV * VV;
    const float* Abt = Att + (size_t)b * VV * VV;
    const unsigned short* y0g = yT + (size_t)bt * 64 * VV;
    const unsigned short* y1g = y0g + (size_t)YELEMS;
    const unsigned short* y2g = y0g + (size_t)2 * YELEMS;
    const int mrow = q * 16 + nbase;
    const int vg   = v0 + mrow;
    const float* Srow = Sbt + (size_t)vg * VV;
    const float* Scol = Sbt + vg;
    const float* Acol = Abt + vg;
    f32x4 zero = {0.f, 0.f, 0.f, 0.f};
    f32x4 acc[4];
    #pragma unroll
    for (int i = 0; i < 4; ++i) acc[i] = zero;
    float da0 = 0.f, da1 = 0.f, adg = 0.f, sdg = 0.f;
    #pragma unroll
    for (int ut = 0; ut < 8; ++ut) {
        const int u0t = ut * 64;
        #pragma unroll
        for (int kk = 0; kk < 2; ++kk) {
            const int ub = u0t + (kk * 4 + g) * 8;
            s16x8 b10 = *(const s16x8*)&y1g[(size_t)(0 * 16 + nbase) * VV + ub];
            s16x8 b11 = *(const s16x8*)&y1g[(size_t)(1 * 16 + nbase) * VV + ub];
            s16x8 b12 = *(const s16x8*)&y1g[(size_t)(2 * 16 + nbase) * VV + ub];
            s16x8 b13 = *(const s16x8*)&y1g[(size_t)(3 * 16 + nbase) * VV + ub];
            f32x4 r0 = *(const f32x4*)(Srow + ub);
            f32x4 r1 = *(const f32x4*)(Srow + ub + 4);
            s16x8 a1, a2;
            #pragma unroll
            for (int e = 0; e < 8; ++e) {
                float sc = Scol[(size_t)(ub + e) * VV];
                float av = Acol[(size_t)(ub + e) * VV];
                float rv = (e < 4) ? r0[e] : r1[e - 4];
                float sm = fminf(sc, rv);
                if (e & 1) da1 += sm; else da0 += sm;
                float c1 = -av * sm;
                float c2 = (av + av) * (sm * sm);
                if (ub + e == vg) { c1 = 0.f; c2 = 0.f; adg = av; sdg = sm; }
                a1[e] = f2bf(c1);
                a2[e] = f2bf(c2);
            }
            acc[0] = __builtin_amdgcn_mfma_f32_16x16x32_bf16(a1, b10, acc[0], 0, 0, 0);
            acc[1] = __builtin_amdgcn_mfma_f32_16x16x32_bf16(a1, b11, acc[1], 0, 0, 0);
            acc[2] = __builtin_amdgcn_mfma_f32_16x16x32_bf16(a1, b12, acc[2], 0, 0, 0);
            acc[3] = __builtin_amdgcn_mfma_f32_16x16x32_bf16(a1, b13, acc[3], 0, 0, 0);
            s16x8 b20 = *(const s16x8*)&y2g[(size_t)(0 * 16 + nbase) * VV + ub];
            s16x8 b21 = *(const s16x8*)&y2g[(size_t)(1 * 16 + nbase) * VV + ub];
            s16x8 b22 = *(const s16x8*)&y2g[(size_t)(2 * 16 + nbase) * VV + ub];
            s16x8 b23 = *(const s16x8*)&y2g[(size_t)(3 * 16 + nbase) * VV + ub];
            acc[0] = __builtin_amdgcn_mfma_f32_16x16x32_bf16(a2, b20, acc[0], 0, 0, 0);
            acc[1] = __builtin_amdgcn_mfma_f32_16x16x32_bf16(a2, b21, acc[1], 0, 0, 0);
            acc[2] = __builtin_amdgcn_mfma_f32_16x16x32_bf16(a2, b22, acc[2], 0, 0, 0);
            acc[3] = __builtin_amdgcn_mfma_f32_16x16x32_bf16(a2, b23, acc[3], 0, 0, 0);
        }
    }
    float da = da0 + da1;
    da  += __shfl_xor(da, 16);  da  += __shfl_xor(da, 32);
    adg += __shfl_xor(adg, 16); adg += __shfl_xor(adg, 32);
    sdg += __shfl_xor(sdg, 16); sdg += __shfl_xor(sdg, 32);
    float* obt = out + (size_t)bt * VV * OO;
    #pragma unroll
    for (int r = 0; r < 4; ++r) {
        const int vloc = q * 16 + g * 4 + r;
        const int src  = g * 4 + r;
        const float Ad = __shfl(adg, src);
        const float dv = __shfl(da,  src);
        const float Sd = __shfl(sdg, src);
        const float Ld = dv - Sd - 1.0f;
        const float w1 = Ad * Ld;
        const float w2 = Ad * (2.0f * Ld * Ld - 1.0f);
        const int vgr = v0 + vloc;
        #pragma unroll
        for (int nt = 0; nt < 4; ++nt) {
            const int oo = nt * 16 + nbase;
            const size_t yi = (size_t)oo * VV + vgr;
            float y0v = bf2f(y0g[yi]);
            float y1v = bf2f(y1g[yi]);
            float y2v = bf2f(y2g[yi]);
            float val = acc[nt][r] + Ad * y0v + w1 * y1v + w2 * y2v;
            obt[(size_t)vgr * OO + oo] = fmaxf(val, 0.0f);
        }
    }
}

extern "C" void kernel_launch(void* const* d_in, const int* in_sizes, int n_in,
                              void* d_out, int out_size, void* d_ws, size_t ws_size,
                              hipStream_t stream) {
    (void)in_sizes; (void)n_in; (void)out_size;
    const float* x   = (const float*)d_in[0];
    const float* Att = (const float*)d_in[1];
    const float* S   = (const float*)d_in[2];
    const float* Th  = (const float*)d_in[3];
    float* outp = (float*)d_out;
    if (ws_size >= (size_t)WS_NEED) {
        unsigned char* ws = (unsigned char*)d_ws;
        hipLaunchKernelGGL(att_kernel, dim3(1024), dim3(256), 0, stream, Att, ws);
        hipLaunchKernelGGL(coef_kernel, dim3(9216), dim3(256), 0, stream, S, Att, ws);
        hipLaunchKernelGGL(y_kernel2, dim3(2048), dim3(256), 0, stream, x, Th, ws);
        hipLaunchKernelGGL(cheb_b, dim3(2048), dim3(256), 0, stream, ws, outp);
    } else {
        unsigned short* yT = (unsigned short*)d_ws;
        hipLaunchKernelGGL(y_kernel_fb, dim3(2048), dim3(256), 0, stream, x, Th, yT);
        hipLaunchKernelGGL(cheb_main_fb, dim3(2048), dim3(256), 0, stream, S, Att, yT, outp);
    }
}